// Round 4
// baseline (371.672 us; speedup 1.0000x reference)
//
#include <hip/hip_runtime.h>
#include <hip/hip_bf16.h>
#include <stdint.h>

#define CCH 256

typedef __attribute__((ext_vector_type(8))) short short8;
typedef __attribute__((ext_vector_type(4))) float f32x4;
typedef __attribute__((ext_vector_type(16))) float f32x16;

__device__ __forceinline__ float lrelu(float v) { return v > 0.f ? v : 0.1f * v; }

__device__ __forceinline__ unsigned short f2bf(float f) {
    __hip_bfloat16 h = __float2bfloat16(f);
    return *reinterpret_cast<unsigned short*>(&h);
}

// async global->LDS, 16B per lane; global addr per-lane, LDS dst wave-uniform (+lane*16)
__device__ __forceinline__ void gl_lds16(const void* g, void* s) {
    __builtin_amdgcn_global_load_lds(
        (const __attribute__((address_space(1))) unsigned int*)(uintptr_t)g,
        (__attribute__((address_space(3))) unsigned int*)(unsigned int)(uintptr_t)s,
        16, 0, 0);
}

// compiler memory fence + hw barrier + fence: raw s_barrier that LDS ops can't cross
__device__ __forceinline__ void pipe_barrier() {
    asm volatile("" ::: "memory");
    __builtin_amdgcn_s_barrier();
    asm volatile("" ::: "memory");
}

// NCHW fp32 -> channel-chunked bf16: out[b][kc][y*64+x][32ci].
// grid (8 kc, 64 y, 16 b), block 256.
__global__ __launch_bounds__(256)
void nhwc_k(const float* __restrict__ in, unsigned short* __restrict__ out)
{
    __shared__ float t[32][65];
    const int tid = threadIdx.x;
    const int kc = blockIdx.x, y = blockIdx.y, b = blockIdx.z;
    const float* src = in + ((size_t)(b * 256 + kc * 32)) * 4096 + y * 64;
#pragma unroll
    for (int i = 0; i < 2; ++i) {
        int idx = tid + i * 256;            // 0..511
        int cl = idx >> 4, xg = idx & 15;
        float4 v = *(const float4*)(src + (size_t)cl * 4096 + xg * 4);
        t[cl][xg * 4 + 0] = v.x; t[cl][xg * 4 + 1] = v.y;
        t[cl][xg * 4 + 2] = v.z; t[cl][xg * 4 + 3] = v.w;
    }
    __syncthreads();
    const int x = tid >> 2, cg = tid & 3;
    union { unsigned short us[8]; uint4 v; } u;
#pragma unroll
    for (int j = 0; j < 8; ++j) u.us[j] = f2bf(t[cg * 8 + j][x]);
    unsigned short* dst = out + (((size_t)(b * 8 + kc) * 4096 + y * 64 + x) * 32 + cg * 8);
    *(uint4*)dst = u.v;
}

// w[co][ci][9] fp32 -> wt[kc][t][q][co][8] bf16 (ci = kc*32 + q*8 + u).
// grid (72, 2), block 256 (= co).
__global__ __launch_bounds__(256)
void wtr_k(const float* __restrict__ w1, const float* __restrict__ w2,
           unsigned short* __restrict__ o1, unsigned short* __restrict__ o2)
{
    const int kc = blockIdx.x / 9, t = blockIdx.x - kc * 9;
    const float* w = blockIdx.y ? w2 : w1;
    unsigned short* o = blockIdx.y ? o2 : o1;
    const int co = threadIdx.x;
#pragma unroll
    for (int q = 0; q < 4; ++q) {
        union { unsigned short us[8]; uint4 v; } u;
#pragma unroll
        for (int uu = 0; uu < 8; ++uu)
            u.us[uu] = f2bf(w[((size_t)co * 256 + kc * 32 + q * 8 + uu) * 9 + t]);
        *(uint4*)(o + ((size_t)((kc * 9 + t) * 4 + q)) * 2048 + co * 8) = u.v;
    }
}

__global__ __launch_bounds__(256)
void zero_pool_k(float* __restrict__ p) { p[blockIdx.x * 256 + threadIdx.x] = 0.f; }

// Implicit-GEMM 3x3 VALID conv, bf16 MFMA 32x32x16.
// M=Cout=256, N=pixels (block 128), K = 72 stages (kc,tap) x 32.
// Block tile 256x128, 4 waves in 2x2, wave tile 128(m) x 64(n): a[4] x b[2] 32x32
// frags per k-half, acc 4x2 f32x16 (128 VGPR). 2 blocks/CU = 2 waves/SIMD (TLP to
// hide staging VALU + ds_read under the co-resident wave's MFMA — R3 showed 1
// wave/SIMD exposes ~1800 cyc/stage serially).
// 32-row x 16B contiguous frag reads -> zero LDS bank conflicts (verified R3).
// Depth-2 software pipeline: 3 LDS buffers, issue STAGE(s+2), compute stage s, counted
// s_waitcnt vmcnt(6) (stage s+2 stays in flight across the barrier) + raw s_barrier.
// Fragment layout (verified on HW in R3): A[row=lane&31][k=8*(lane>>5)+j],
// B[col=lane&31][k=8*(lane>>5)+j]; D: col(px)=lane&31, row(co)=(reg&3)+8*(reg>>2)+4*(lane>>5).
// im: [b][kc][WIN*WIN][32] bf16; wt: [kc][t][q][co=256][8] bf16.
// POOL=0: h1 out [b][kc'][NVAL][32] (bias+lrelu, bf16). POOL=1: sum -> atomicAdd pool.
// grid (ceil(NVAL/128), 16 b), block 256, 2 blocks/CU (LDS 74112 B).
template<int POOL, int WIN, int WOUT>
__global__ __launch_bounds__(256, 2)
void convmm_k(const unsigned short* __restrict__ im, const unsigned short* __restrict__ wt,
              const float* __restrict__ bias, unsigned short* __restrict__ outp,
              float* __restrict__ pool)
{
    constexpr int HINPIX = WIN * WIN;
    constexpr int NVAL   = WOUT * WOUT;
    // Per buffer: A = 4 q-planes [256 co][8], plane stride 2056 shorts (+16B pad);
    //             B = 4 q-planes [128 px][8], plane stride 1032 shorts (+16B pad).
    constexpr int NB = 4 * 2056 + 4 * 1032;   // 12352 shorts = 24704 B per buffer
    __shared__ __align__(16) short Ls[3 * NB];

    const int tid  = threadIdx.x;
    const int wave = tid >> 6;
    const int lane = tid & 63;
    const int l31  = lane & 31;
    const int hi   = lane >> 5;
    const int wm   = (wave & 1) * 128;     // m offset of wave tile (co)
    const int wn   = (wave >> 1) * 64;     // n offset of wave tile (px)
    const int nb0  = blockIdx.x * 128;
    const int b    = blockIdx.y;

    // A staging: wave stages plane q=wave; 4 calls h, rows h*64+lane (8 shorts each)
    const unsigned short* abase = wt + (size_t)wave * 2048 + (size_t)lane * 8;
    // B staging: wave stages plane q=wave; 2 calls h, px rows h*64+lane
    size_t bofs[2];
#pragma unroll
    for (int h = 0; h < 2; ++h) {
        int nn = nb0 + h * 64 + lane;
        if (nn > NVAL - 1) nn = NVAL - 1;
        int y = nn / WOUT, x = nn - y * WOUT;
        bofs[h] = ((size_t)(b * 8) * HINPIX + (size_t)y * WIN + x) * 32 + wave * 8;
    }

    f32x16 acc[4][2];
#pragma unroll
    for (int i = 0; i < 4; ++i)
#pragma unroll
        for (int j = 0; j < 2; ++j)
#pragma unroll
            for (int e = 0; e < 16; ++e) acc[i][j][e] = 0.f;

    // issue one stage's 6 global_load_lds into LDS buffer `buf`
    auto stage = [&](int ss, short* buf) {
        const int kc = ss / 9, t = ss - kc * 9;
        const int ky = t / 3, kx = t - ky * 3;
        const size_t aoff = (size_t)ss * 8192;
        const size_t boff = ((size_t)kc * HINPIX + (size_t)ky * WIN + kx) * 32;
        short* al = buf + wave * 2056;
        short* bl = buf + 4 * 2056 + wave * 1032;
#pragma unroll
        for (int h = 0; h < 4; ++h)
            gl_lds16(abase + aoff + h * 512, al + h * 512);
#pragma unroll
        for (int h = 0; h < 2; ++h)
            gl_lds16(im + bofs[h] + boff, bl + h * 512);
    };

    // consume one staged buffer: 12 ds_read_b128 + 16 MFMA (2 k-halves)
    auto compute = [&](const short* buf) {
        const short* Ab = buf;
        const short* Bb = buf + 4 * 2056;
#pragma unroll
        for (int kh = 0; kh < 2; ++kh) {
            const short* ap = Ab + (kh * 2 + hi) * 2056;
            const short* bp = Bb + (kh * 2 + hi) * 1032;
            short8 a[4], bb[2];
#pragma unroll
            for (int mi = 0; mi < 4; ++mi)
                a[mi] = *(const short8*)(ap + (wm + mi * 32 + l31) * 8);
#pragma unroll
            for (int nj = 0; nj < 2; ++nj)
                bb[nj] = *(const short8*)(bp + (wn + nj * 32 + l31) * 8);
            __builtin_amdgcn_s_setprio(1);
#pragma unroll
            for (int mi = 0; mi < 4; ++mi)
#pragma unroll
                for (int nj = 0; nj < 2; ++nj)
                    acc[mi][nj] = __builtin_amdgcn_mfma_f32_32x32x16_bf16(
                        a[mi], bb[nj], acc[mi][nj], 0, 0, 0);
            __builtin_amdgcn_s_setprio(0);
        }
    };

    short* B0 = Ls;
    short* B1 = Ls + NB;
    short* B2 = Ls + 2 * NB;

    // prologue: fill pipeline with stages 0 and 1 (12 loads outstanding)
    stage(0, B0);
    stage(1, B1);
    asm volatile("s_waitcnt vmcnt(6)" ::: "memory");   // stage 0 landed; stage 1 in flight
    pipe_barrier();

    short *c0 = B0, *c1 = B1, *c2 = B2;
    // invariant at top of iter s: c0 holds stage s (ready), c1 holds stage s+1
    // (in flight or ready), c2 is free (its last readers barrier-retired).
    for (int s = 0; s < 70; ++s) {
        stage(s + 2, c2);                               // 6 more loads in flight
        compute(c0);
        // retire stage s+1's loads (oldest 6 of <=12); stage s+2 stays in flight
        asm volatile("s_waitcnt vmcnt(6)" ::: "memory");
        pipe_barrier();
        short* t = c0; c0 = c1; c1 = c2; c2 = t;
    }
    // s = 70: no more staging; drain stage 71 before its compute
    compute(c0);
    asm volatile("s_waitcnt vmcnt(0)" ::: "memory");
    pipe_barrier();
    // s = 71
    compute(c1);

    // D layout per 32x32 tile: col(px)=l31, row(co)=(reg&3)+8*(reg>>2)+4*hi
    const int co_l = wm + 4 * hi;
    if (!POOL) {
#pragma unroll
        for (int mi = 0; mi < 4; ++mi) {
            const int kc = (wm >> 5) + mi;
            float4 bv[4];
#pragma unroll
            for (int g = 0; g < 4; ++g)
                bv[g] = *(const float4*)(bias + co_l + mi * 32 + 8 * g);
            unsigned short* dstp = outp + ((size_t)(b * 8 + kc) * NVAL) * 32 + 4 * hi;
#pragma unroll
            for (int nj = 0; nj < 2; ++nj) {
                int nn = nb0 + wn + nj * 32 + l31;
                if (nn < NVAL) {
                    unsigned short* dq = dstp + (size_t)nn * 32;
#pragma unroll
                    for (int g = 0; g < 4; ++g) {
                        ushort4 pk = make_ushort4(
                            f2bf(lrelu(acc[mi][nj][g * 4 + 0] + bv[g].x)),
                            f2bf(lrelu(acc[mi][nj][g * 4 + 1] + bv[g].y)),
                            f2bf(lrelu(acc[mi][nj][g * 4 + 2] + bv[g].z)),
                            f2bf(lrelu(acc[mi][nj][g * 4 + 3] + bv[g].w)));
                        *(ushort4*)(dq + 8 * g) = pk;
                    }
                }
            }
        }
    } else {
#pragma unroll
        for (int mi = 0; mi < 4; ++mi) {
            float bb[16];
#pragma unroll
            for (int g = 0; g < 4; ++g) {
                float4 v = *(const float4*)(bias + co_l + mi * 32 + 8 * g);
                bb[g * 4 + 0] = v.x; bb[g * 4 + 1] = v.y;
                bb[g * 4 + 2] = v.z; bb[g * 4 + 3] = v.w;
            }
            float s[16];
#pragma unroll
            for (int e = 0; e < 16; ++e) s[e] = 0.f;
#pragma unroll
            for (int nj = 0; nj < 2; ++nj) {
                int nn = nb0 + wn + nj * 32 + l31;
                if (nn < NVAL) {
#pragma unroll
                    for (int e = 0; e < 16; ++e)
                        s[e] += lrelu(acc[mi][nj][e] + bb[e]);
                }
            }
#pragma unroll
            for (int off = 1; off < 32; off <<= 1)
#pragma unroll
                for (int e = 0; e < 16; ++e)
                    s[e] += __shfl_xor(s[e], off, 64);
            if (l31 == 0) {
                float* pp = pool + b * 256 + co_l + mi * 32;
#pragma unroll
                for (int g = 0; g < 4; ++g)
#pragma unroll
                    for (int r = 0; r < 4; ++r)
                        atomicAdd(pp + 8 * g + r, s[g * 4 + r]);
            }
        }
    }
}

// kern[b][o] = (1/3600) * sum_c pool[b][c]*w3[o][c] + b3[o]
__global__ __launch_bounds__(256)
void kern_gemm_k(const float* __restrict__ p, const float* __restrict__ w3,
                 const float* __restrict__ b3, float* __restrict__ kern)
{
    const int b = blockIdx.y;
    const int o = blockIdx.x * 256 + threadIdx.x;
    __shared__ float pv[CCH];
    pv[threadIdx.x] = p[b * CCH + threadIdx.x] * (1.f / 3600.f);
    __syncthreads();
    float acc = b3[o];
    const float* wr = w3 + (size_t)o * CCH;
#pragma unroll 4
    for (int c = 0; c < CCH; c += 4) {
        float4 wv = *(const float4*)(wr + c);
        acc += wv.x * pv[c] + wv.y * pv[c + 1] + wv.z * pv[c + 2] + wv.w * pv[c + 3];
    }
    kern[(size_t)b * (9 * CCH) + o] = acc;
}

// Per-sample depthwise 3x3 SAME + bias, fp32, LDS-staged.
// One block (256 thr) per (b,c) plane. LDS tile 66 rows x 67 stride, zero halo.
__global__ __launch_bounds__(256)
void dw_k(const float* __restrict__ x, const float* __restrict__ kern,
          const float* __restrict__ bias, float* __restrict__ out)
{
    __shared__ float t[66 * 67];
    const int tid = threadIdx.x;
    const int bc = blockIdx.x;
    const int c = bc & (CCH - 1);
    const int b = bc >> 8;

#pragma unroll
    for (int i = 0; i < 18; ++i) {
        int idx = tid + i * 256;
        if (idx < 66 * 67) t[idx] = 0.f;
    }

    const float* kp = kern + (size_t)b * (9 * CCH) + c * 9;
    float k[9];
#pragma unroll
    for (int q = 0; q < 9; ++q) k[q] = kp[q];
    const float bs = bias[c];
    const float* xp = x + (size_t)bc * 4096;
    float* op = out + (size_t)bc * 4096;
    __syncthreads();

#pragma unroll
    for (int i = 0; i < 4; ++i) {
        int p4 = tid + i * 256;            // float4 index 0..1023
        float4 v = *(const float4*)(xp + p4 * 4);
        int yy = p4 >> 4, xx = (p4 & 15) * 4;
        float* d = &t[(yy + 1) * 67 + 1 + xx];
        d[0] = v.x; d[1] = v.y; d[2] = v.z; d[3] = v.w;
    }
    __syncthreads();

#pragma unroll
    for (int i = 0; i < 4; ++i) {
        int p4 = tid + i * 256;
        int yy = p4 >> 4, xx = (p4 & 15) * 4;
        float r[3][6];
#pragma unroll
        for (int dy = 0; dy < 3; ++dy)
#pragma unroll
            for (int dx = 0; dx < 6; ++dx)
                r[dy][dx] = t[(yy + dy) * 67 + xx + dx];
        float4 o;
        float* ov = (float*)&o;
#pragma unroll
        for (int j = 0; j < 4; ++j) {
            float a = bs;
#pragma unroll
            for (int dy = 0; dy < 3; ++dy)
#pragma unroll
                for (int dx = 0; dx < 3; ++dx)
                    a += k[dy * 3 + dx] * r[dy][j + dx];
            ov[j] = a;
        }
        *(float4*)(op + p4 * 4) = o;
    }
}

extern "C" void kernel_launch(void* const* d_in, const int* in_sizes, int n_in,
                              void* d_out, int out_size, void* d_ws, size_t ws_size,
                              hipStream_t stream)
{
    const float* x    = (const float*)d_in[0];
    const float* kin  = (const float*)d_in[1];
    const float* w1   = (const float*)d_in[2];
    const float* b1   = (const float*)d_in[3];
    const float* w2   = (const float*)d_in[4];
    const float* b2   = (const float*)d_in[5];
    const float* w3   = (const float*)d_in[6];
    const float* b3   = (const float*)d_in[7];
    const float* bias = (const float*)d_in[8];

    // ws: imA [16][8][4096][32] bf16 | h1 [16][8][3844][32] bf16 (+slack) | w1t | w2t | pool | kern
    unsigned short* imA = (unsigned short*)d_ws;
    unsigned short* h1  = imA + (size_t)16 * 8 * 4096 * 32;
    unsigned short* w1t = h1 + (size_t)16 * 8 * 3844 * 32 + 8192;   // slack for clamped-tap reads
    unsigned short* w2t = w1t + (size_t)72 * 4 * 2048;
    float* pool = (float*)(w2t + (size_t)72 * 4 * 2048);
    float* kern = pool + 16 * 256;

    float* out = (float*)d_out;

    hipLaunchKernelGGL(zero_pool_k, dim3(16), dim3(256), 0, stream, pool);
    hipLaunchKernelGGL(nhwc_k, dim3(8, 64, 16), dim3(256), 0, stream, kin, imA);
    hipLaunchKernelGGL(wtr_k, dim3(72, 2), dim3(256), 0, stream, w1, w2, w1t, w2t);
    hipLaunchKernelGGL((convmm_k<0, 64, 62>), dim3(31, 16), dim3(256), 0, stream,
                       imA, w1t, b1, h1, (float*)nullptr);
    hipLaunchKernelGGL((convmm_k<1, 62, 60>), dim3(29, 16), dim3(256), 0, stream,
                       h1, w2t, b2, (unsigned short*)nullptr, pool);
    hipLaunchKernelGGL(kern_gemm_k, dim3(9, 16), dim3(256), 0, stream, pool, w3, b3, kern);
    hipLaunchKernelGGL(dw_k, dim3(16 * 256), dim3(256), 0, stream, x, kern, bias, out);
}

// Round 5
// 332.600 us; speedup vs baseline: 1.1175x; 1.1175x over previous
//
#include <hip/hip_runtime.h>
#include <hip/hip_bf16.h>
#include <stdint.h>

#define CCH 256

typedef __attribute__((ext_vector_type(8))) short short8;
typedef __attribute__((ext_vector_type(4))) float f32x4;

__device__ __forceinline__ float lrelu(float v) { return v > 0.f ? v : 0.1f * v; }

__device__ __forceinline__ unsigned short f2bf(float f) {
    __hip_bfloat16 h = __float2bfloat16(f);
    return *reinterpret_cast<unsigned short*>(&h);
}

// async global->LDS, 16B per lane; global addr per-lane, LDS dst wave-uniform (+lane*16)
__device__ __forceinline__ void gl_lds16(const void* g, void* s) {
    __builtin_amdgcn_global_load_lds(
        (const __attribute__((address_space(1))) unsigned int*)(uintptr_t)g,
        (__attribute__((address_space(3))) unsigned int*)(unsigned int)(uintptr_t)s,
        16, 0, 0);
}

// compiler memory fence + hw barrier + fence: raw s_barrier that LDS ops can't cross
__device__ __forceinline__ void pipe_barrier() {
    asm volatile("" ::: "memory");
    __builtin_amdgcn_s_barrier();
    asm volatile("" ::: "memory");
}

// NCHW fp32 -> channel-chunked bf16: out[b][kc][y*64+x][32ci].
// grid (8 kc, 64 y, 16 b), block 256.
__global__ __launch_bounds__(256)
void nhwc_k(const float* __restrict__ in, unsigned short* __restrict__ out)
{
    __shared__ float t[32][65];
    const int tid = threadIdx.x;
    const int kc = blockIdx.x, y = blockIdx.y, b = blockIdx.z;
    const float* src = in + ((size_t)(b * 256 + kc * 32)) * 4096 + y * 64;
#pragma unroll
    for (int i = 0; i < 2; ++i) {
        int idx = tid + i * 256;            // 0..511
        int cl = idx >> 4, xg = idx & 15;
        float4 v = *(const float4*)(src + (size_t)cl * 4096 + xg * 4);
        t[cl][xg * 4 + 0] = v.x; t[cl][xg * 4 + 1] = v.y;
        t[cl][xg * 4 + 2] = v.z; t[cl][xg * 4 + 3] = v.w;
    }
    __syncthreads();
    const int x = tid >> 2, cg = tid & 3;
    union { unsigned short us[8]; uint4 v; } u;
#pragma unroll
    for (int j = 0; j < 8; ++j) u.us[j] = f2bf(t[cg * 8 + j][x]);
    unsigned short* dst = out + (((size_t)(b * 8 + kc) * 4096 + y * 64 + x) * 32 + cg * 8);
    *(uint4*)dst = u.v;
}

// w[co][ci][9] fp32 -> wt in FRAGMENT-MAJOR order: wt[ss=kc*9+t][f=0..15][l=0..63][8] bf16
// where lane l of frag f holds co = f*16 + (l&15), ci = kc*32 + (l>>4)*8 + u.
// In convmm a wave then reads frag f as ONE contiguous 1KiB block (lane*16B linear)
// -> zero LDS bank conflicts, and staging/ds_read addressing is base + f*1024.
// grid (72, 2), block 256.
__global__ __launch_bounds__(256)
void wtr_k(const float* __restrict__ w1, const float* __restrict__ w2,
           unsigned short* __restrict__ o1, unsigned short* __restrict__ o2)
{
    const int ss = blockIdx.x;
    const int kc = ss / 9, t = ss - kc * 9;
    const float* w = blockIdx.y ? w2 : w1;
    unsigned short* o = blockIdx.y ? o2 : o1;
#pragma unroll
    for (int rep = 0; rep < 4; ++rep) {
        int slot = threadIdx.x + rep * 256;      // 0..1023: (frag f, lane l)
        int f = slot >> 6, l = slot & 63;
        int co = f * 16 + (l & 15);
        int q  = l >> 4;
        union { unsigned short us[8]; uint4 v; } u;
#pragma unroll
        for (int uu = 0; uu < 8; ++uu)
            u.us[uu] = f2bf(w[((size_t)co * 256 + kc * 32 + q * 8 + uu) * 9 + t]);
        *(uint4*)(o + (size_t)ss * 8192 + slot * 8) = u.v;
    }
}

__global__ __launch_bounds__(256)
void zero_pool_k(float* __restrict__ p) { p[blockIdx.x * 256 + threadIdx.x] = 0.f; }

// Implicit-GEMM 3x3 VALID conv, bf16 MFMA 16x16x32 (R1 structure, best measured).
// M=Cout=256, N=pixels (block 128), K = 72 stages (kc,tap) x 32.
// Block tile 256x128, 4 waves in 2x2, wave tile 128(m) x 64(n): a[8] x b[4] frags,
// acc 8x4 f32x4. 2 blocks/CU = 2 waves/SIMD.
// FRAGMENT-MAJOR LDS: buffer = A[16 frags][64 lanes][8] (16KB) + B[8 frags][64][8] (8KB).
// Every frag read is 1KiB contiguous per wave (lane*16B linear) -> zero bank conflicts
// (R1's quad-plane layout cost 6.86M conflict cycles). Per-lane operand data is
// bit-identical to R1: A lane l of frag f: co=f*16+(l&15), k-chunk=l>>4;
// B lane l of frag p: px=p*16+(l&15), k-chunk=l>>4. B reorder done via per-lane
// GLOBAL src addrs in global_load_lds (im layout unchanged; 1KB contiguous per frag).
// Depth-2 software pipeline: 3 LDS buffers, issue STAGE(s+2), compute stage s, counted
// s_waitcnt vmcnt(6) + raw s_barrier. setprio(1) around the 32-MFMA cluster.
// im: [b][kc][WIN*WIN][32] bf16; wt: [ss][16][64][8] bf16 (fragment-major).
// POOL=0: h1 out [b][kc'][NVAL][32] (bias+lrelu, bf16). POOL=1: sum -> atomicAdd pool.
// grid (ceil(NVAL/128), 16 b), block 256, 2 blocks/CU (LDS 73728 B).
template<int POOL, int WIN, int WOUT>
__global__ __launch_bounds__(256, 2)
void convmm_k(const unsigned short* __restrict__ im, const unsigned short* __restrict__ wt,
              const float* __restrict__ bias, unsigned short* __restrict__ outp,
              float* __restrict__ pool)
{
    constexpr int HINPIX = WIN * WIN;
    constexpr int NVAL   = WOUT * WOUT;
    constexpr int NB = 16 * 512 + 8 * 512;    // 12288 shorts = 24576 B per buffer
    __shared__ __align__(16) short Ls[3 * NB]; // 73728 B

    const int tid  = threadIdx.x;
    const int wave = tid >> 6;
    const int lane = tid & 63;
    const int quad = lane >> 4;
    const int l15  = lane & 15;
    const int wm   = (wave & 1) * 128;     // m offset of wave tile (co)
    const int wn   = (wave >> 1) * 64;     // n offset of wave tile (px)
    const int nb0  = blockIdx.x * 128;
    const int b    = blockIdx.y;

    // A staging: wave w stages frags w*4..w*4+3 (1KB each, linear src+dst)
    const unsigned short* abase = wt + (size_t)(wave * 4) * 512 + (size_t)lane * 8;
    // B staging: wave w stages px-frags 2w, 2w+1; lane l -> px = pfrag*16+(l&15),
    // 16B chunk (l>>4)*8 of the px row. Per-lane global src, linear LDS dst.
    size_t bofs[2];
#pragma unroll
    for (int h = 0; h < 2; ++h) {
        int nn = nb0 + (wave * 2 + h) * 16 + l15;
        if (nn > NVAL - 1) nn = NVAL - 1;
        int y = nn / WOUT, x = nn - y * WOUT;
        bofs[h] = ((size_t)(b * 8) * HINPIX + (size_t)y * WIN + x) * 32 + quad * 8;
    }

    f32x4 acc[8][4];
#pragma unroll
    for (int i = 0; i < 8; ++i)
#pragma unroll
        for (int j = 0; j < 4; ++j) { f32x4 z = {0.f, 0.f, 0.f, 0.f}; acc[i][j] = z; }

    // issue one stage's 6 global_load_lds into LDS buffer `buf`
    auto stage = [&](int ss, short* buf) {
        const int kc = ss / 9, t = ss - kc * 9;
        const int ky = t / 3, kx = t - ky * 3;
        const size_t aoff = (size_t)ss * 8192;
        const size_t boff = ((size_t)kc * HINPIX + (size_t)ky * WIN + kx) * 32;
        short* bl = buf + 16 * 512;
#pragma unroll
        for (int h = 0; h < 4; ++h)
            gl_lds16(abase + aoff + h * 512, buf + (wave * 4 + h) * 512);
#pragma unroll
        for (int h = 0; h < 2; ++h)
            gl_lds16(im + bofs[h] + boff, bl + (wave * 2 + h) * 512);
    };

    // consume one staged buffer: 12 ds_read_b128 (all 1KB-linear per wave) + 32 MFMA
    auto compute = [&](const short* buf) {
        const short* ap = buf + (size_t)(wave & 1) * 8 * 512 + lane * 8;
        const short* bp = buf + 16 * 512 + (size_t)(wave >> 1) * 4 * 512 + lane * 8;
        short8 a[8], bfr[4];
#pragma unroll
        for (int i = 0; i < 8; ++i)
            a[i]  = *(const short8*)(ap + i * 512);
#pragma unroll
        for (int j = 0; j < 4; ++j)
            bfr[j] = *(const short8*)(bp + j * 512);
        __builtin_amdgcn_s_setprio(1);
#pragma unroll
        for (int i = 0; i < 8; ++i)
#pragma unroll
            for (int j = 0; j < 4; ++j)
                acc[i][j] = __builtin_amdgcn_mfma_f32_16x16x32_bf16(a[i], bfr[j], acc[i][j], 0, 0, 0);
        __builtin_amdgcn_s_setprio(0);
    };

    short* B0 = Ls;
    short* B1 = Ls + NB;
    short* B2 = Ls + 2 * NB;

    // prologue: fill pipeline with stages 0 and 1 (12 loads outstanding)
    stage(0, B0);
    stage(1, B1);
    asm volatile("s_waitcnt vmcnt(6)" ::: "memory");   // stage 0 landed; stage 1 in flight
    pipe_barrier();

    short *c0 = B0, *c1 = B1, *c2 = B2;
    // invariant at top of iter s: c0 holds stage s (ready), c1 holds stage s+1
    // (in flight or ready), c2 is free (its last readers barrier-retired).
    for (int s = 0; s < 70; ++s) {
        stage(s + 2, c2);                               // 6 more loads in flight
        compute(c0);
        // retire stage s+1's loads (oldest 6 of <=12); stage s+2 stays in flight
        asm volatile("s_waitcnt vmcnt(6)" ::: "memory");
        pipe_barrier();
        short* t = c0; c0 = c1; c1 = c2; c2 = t;
    }
    // s = 70: no more staging; drain stage 71 before its compute
    compute(c0);
    asm volatile("s_waitcnt vmcnt(0)" ::: "memory");
    pipe_barrier();
    // s = 71
    compute(c1);

    // D layout: col(px)=l15, row(co)=quad*4+reg
    const int co_l = wm + quad * 4;
    if (!POOL) {
#pragma unroll
        for (int i = 0; i < 8; ++i) {
            const int c0i = co_l + i * 16;
            float4 bv = *(const float4*)(bias + c0i);
            unsigned short* dstp = outp + ((size_t)(b * 8 + (c0i >> 5)) * NVAL) * 32 + (c0i & 31);
#pragma unroll
            for (int j = 0; j < 4; ++j) {
                int nn = nb0 + wn + j * 16 + l15;
                if (nn < NVAL) {
                    ushort4 pk = make_ushort4(
                        f2bf(lrelu(acc[i][j].x + bv.x)),
                        f2bf(lrelu(acc[i][j].y + bv.y)),
                        f2bf(lrelu(acc[i][j].z + bv.z)),
                        f2bf(lrelu(acc[i][j].w + bv.w)));
                    *(ushort4*)(dstp + (size_t)nn * 32) = pk;
                }
            }
        }
    } else {
#pragma unroll
        for (int i = 0; i < 8; ++i) {
            const int c0i = co_l + i * 16;
            float4 bv = *(const float4*)(bias + c0i);
            float s0 = 0.f, s1 = 0.f, s2 = 0.f, s3 = 0.f;
#pragma unroll
            for (int j = 0; j < 4; ++j) {
                int nn = nb0 + wn + j * 16 + l15;
                if (nn < NVAL) {
                    s0 += lrelu(acc[i][j].x + bv.x);
                    s1 += lrelu(acc[i][j].y + bv.y);
                    s2 += lrelu(acc[i][j].z + bv.z);
                    s3 += lrelu(acc[i][j].w + bv.w);
                }
            }
#pragma unroll
            for (int off = 1; off < 16; off <<= 1) {
                s0 += __shfl_xor(s0, off, 64);
                s1 += __shfl_xor(s1, off, 64);
                s2 += __shfl_xor(s2, off, 64);
                s3 += __shfl_xor(s3, off, 64);
            }
            if (l15 == 0) {
                float* pp = pool + b * 256 + c0i;
                atomicAdd(pp + 0, s0); atomicAdd(pp + 1, s1);
                atomicAdd(pp + 2, s2); atomicAdd(pp + 3, s3);
            }
        }
    }
}

// kern[b][o] = (1/3600) * sum_c pool[b][c]*w3[o][c] + b3[o]
__global__ __launch_bounds__(256)
void kern_gemm_k(const float* __restrict__ p, const float* __restrict__ w3,
                 const float* __restrict__ b3, float* __restrict__ kern)
{
    const int b = blockIdx.y;
    const int o = blockIdx.x * 256 + threadIdx.x;
    __shared__ float pv[CCH];
    pv[threadIdx.x] = p[b * CCH + threadIdx.x] * (1.f / 3600.f);
    __syncthreads();
    float acc = b3[o];
    const float* wr = w3 + (size_t)o * CCH;
#pragma unroll 4
    for (int c = 0; c < CCH; c += 4) {
        float4 wv = *(const float4*)(wr + c);
        acc += wv.x * pv[c] + wv.y * pv[c + 1] + wv.z * pv[c + 2] + wv.w * pv[c + 3];
    }
    kern[(size_t)b * (9 * CCH) + o] = acc;
}

// Per-sample depthwise 3x3 SAME + bias, fp32, LDS-staged.
// One block (256 thr) per (b,c) plane. LDS tile 66 rows x 67 stride, zero halo.
__global__ __launch_bounds__(256)
void dw_k(const float* __restrict__ x, const float* __restrict__ kern,
          const float* __restrict__ bias, float* __restrict__ out)
{
    __shared__ float t[66 * 67];
    const int tid = threadIdx.x;
    const int bc = blockIdx.x;
    const int c = bc & (CCH - 1);
    const int b = bc >> 8;

#pragma unroll
    for (int i = 0; i < 18; ++i) {
        int idx = tid + i * 256;
        if (idx < 66 * 67) t[idx] = 0.f;
    }

    const float* kp = kern + (size_t)b * (9 * CCH) + c * 9;
    float k[9];
#pragma unroll
    for (int q = 0; q < 9; ++q) k[q] = kp[q];
    const float bs = bias[c];
    const float* xp = x + (size_t)bc * 4096;
    float* op = out + (size_t)bc * 4096;
    __syncthreads();

#pragma unroll
    for (int i = 0; i < 4; ++i) {
        int p4 = tid + i * 256;            // float4 index 0..1023
        float4 v = *(const float4*)(xp + p4 * 4);
        int yy = p4 >> 4, xx = (p4 & 15) * 4;
        float* d = &t[(yy + 1) * 67 + 1 + xx];
        d[0] = v.x; d[1] = v.y; d[2] = v.z; d[3] = v.w;
    }
    __syncthreads();

#pragma unroll
    for (int i = 0; i < 4; ++i) {
        int p4 = tid + i * 256;
        int yy = p4 >> 4, xx = (p4 & 15) * 4;
        float r[3][6];
#pragma unroll
        for (int dy = 0; dy < 3; ++dy)
#pragma unroll
            for (int dx = 0; dx < 6; ++dx)
                r[dy][dx] = t[(yy + dy) * 67 + xx + dx];
        float4 o;
        float* ov = (float*)&o;
#pragma unroll
        for (int j = 0; j < 4; ++j) {
            float a = bs;
#pragma unroll
            for (int dy = 0; dy < 3; ++dy)
#pragma unroll
                for (int dx = 0; dx < 3; ++dx)
                    a += k[dy * 3 + dx] * r[dy][j + dx];
            ov[j] = a;
        }
        *(float4*)(op + p4 * 4) = o;
    }
}

extern "C" void kernel_launch(void* const* d_in, const int* in_sizes, int n_in,
                              void* d_out, int out_size, void* d_ws, size_t ws_size,
                              hipStream_t stream)
{
    const float* x    = (const float*)d_in[0];
    const float* kin  = (const float*)d_in[1];
    const float* w1   = (const float*)d_in[2];
    const float* b1   = (const float*)d_in[3];
    const float* w2   = (const float*)d_in[4];
    const float* b2   = (const float*)d_in[5];
    const float* w3   = (const float*)d_in[6];
    const float* b3   = (const float*)d_in[7];
    const float* bias = (const float*)d_in[8];

    // ws: imA [16][8][4096][32] bf16 | h1 [16][8][3844][32] bf16 (+slack) | w1t | w2t | pool | kern
    unsigned short* imA = (unsigned short*)d_ws;
    unsigned short* h1  = imA + (size_t)16 * 8 * 4096 * 32;
    unsigned short* w1t = h1 + (size_t)16 * 8 * 3844 * 32 + 8192;   // slack for clamped-tap reads
    unsigned short* w2t = w1t + (size_t)72 * 8192;
    float* pool = (float*)(w2t + (size_t)72 * 8192);
    float* kern = pool + 16 * 256;

    float* out = (float*)d_out;

    hipLaunchKernelGGL(zero_pool_k, dim3(16), dim3(256), 0, stream, pool);
    hipLaunchKernelGGL(nhwc_k, dim3(8, 64, 16), dim3(256), 0, stream, kin, imA);
    hipLaunchKernelGGL(wtr_k, dim3(72, 2), dim3(256), 0, stream, w1, w2, w1t, w2t);
    hipLaunchKernelGGL((convmm_k<0, 64, 62>), dim3(31, 16), dim3(256), 0, stream,
                       imA, w1t, b1, h1, (float*)nullptr);
    hipLaunchKernelGGL((convmm_k<1, 62, 60>), dim3(29, 16), dim3(256), 0, stream,
                       h1, w2t, b2, (unsigned short*)nullptr, pool);
    hipLaunchKernelGGL(kern_gemm_k, dim3(9, 16), dim3(256), 0, stream, pool, w3, b3, kern);
    hipLaunchKernelGGL(dw_k, dim3(16 * 256), dim3(256), 0, stream, x, kern, bias, out);
}